// Round 1
// baseline (7468.105 us; speedup 1.0000x reference)
//
#include <hip/hip_runtime.h>
#include <math.h>

namespace {

constexpr int NB   = 4;
constexpr int SEQ  = 512;
constexpr int HS_  = 512;
constexpr int NH_  = 8;
constexpr int NL_  = 6;
constexpr int FF_  = 2048;
constexpr int VOC_ = 32000;
constexpr int MT   = NB * SEQ;   // 2048 token rows

// ---------------- embedding + sinusoidal positional encoding ----------------
__global__ __launch_bounds__(256)
void k_embed(const int* __restrict__ tok, const float* __restrict__ emb,
             float* __restrict__ out)
{
    int row = blockIdx.x;            // b*SEQ + s
    int s = row & (SEQ - 1);
    int t = tok[row];
    const float* e = emb + (size_t)t * HS_;
    float* o = out + (size_t)row * HS_;
    for (int i = threadIdx.x; i < HS_; i += 256) {
        int half = i >> 1;
        float freq = powf(10000.0f, -(float)half / (float)HS_);
        float ang = (float)s * freq;
        float pe = (i & 1) ? cosf(ang) : sinf(ang);
        o[i] = e[i] + pe;
    }
}

// ---------------- layernorm: one wave per row of 512 ----------------
__global__ __launch_bounds__(64)
void k_ln(const float* __restrict__ in, const float* __restrict__ g,
          const float* __restrict__ b, float* __restrict__ out)
{
    int row = blockIdx.x;
    int lane = threadIdx.x;
    const float* x = in + (size_t)row * HS_;
    float v[8], s = 0.f, s2 = 0.f;
    #pragma unroll
    for (int i = 0; i < 8; i++) {
        v[i] = x[lane + i * 64];
        s += v[i];
        s2 += v[i] * v[i];
    }
    #pragma unroll
    for (int off = 32; off; off >>= 1) { s += __shfl_xor(s, off); s2 += __shfl_xor(s2, off); }
    float mean = s * (1.0f / HS_);
    float var  = s2 * (1.0f / HS_) - mean * mean;
    float rstd = rsqrtf(var + 1e-5f);
    float* o = out + (size_t)row * HS_;
    #pragma unroll
    for (int i = 0; i < 8; i++) {
        int e = lane + i * 64;
        o[e] = (v[i] - mean) * rstd * g[e] + b[e];
    }
}

// ---------------- fp32 tiled GEMM: C[M,N] = A[M,K] @ W[K,N] (+bias)(+resid)(relu) ----------------
// 64x64 tile, BK=16, 256 threads, 4x4 per thread.
// NOTE: C and resid may alias (in-place residual) -> no __restrict__ on them.
template<int RELU>
__global__ __launch_bounds__(256)
void k_gemm(const float* __restrict__ A, const float* __restrict__ W,
            const float* __restrict__ bias, const float* resid,
            float* C, int M, int N, int K)
{
    __shared__ float As[16][68];
    __shared__ float Bs[16][68];
    const int tid = threadIdx.x;
    const int bn = blockIdx.x * 64;
    const int bm = blockIdx.y * 64;
    const int tx = tid & 15, ty = tid >> 4;
    const int am = tid >> 2, ak = (tid & 3) << 2;   // A tile 64x16, float4 per thread
    const int bk = tid >> 4, bn2 = (tid & 15) << 2; // W tile 16x64, float4 per thread

    const float* Ap = A + (size_t)(bm + am) * K + ak;
    const float* Wp = W + (size_t)bk * N + bn + bn2;

    float acc[4][4] = {};
    for (int k0 = 0; k0 < K; k0 += 16) {
        float4 av = *(const float4*)(Ap + k0);
        float4 bv = *(const float4*)(Wp + (size_t)k0 * N);
        __syncthreads();
        As[ak + 0][am] = av.x;
        As[ak + 1][am] = av.y;
        As[ak + 2][am] = av.z;
        As[ak + 3][am] = av.w;
        *(float4*)&Bs[bk][bn2] = bv;
        __syncthreads();
        #pragma unroll
        for (int k = 0; k < 16; k++) {
            float4 a4 = *(const float4*)&As[k][ty << 2];
            float4 b4 = *(const float4*)&Bs[k][tx << 2];
            float ar[4] = {a4.x, a4.y, a4.z, a4.w};
            float br[4] = {b4.x, b4.y, b4.z, b4.w};
            #pragma unroll
            for (int i = 0; i < 4; i++)
                #pragma unroll
                for (int j = 0; j < 4; j++)
                    acc[i][j] = fmaf(ar[i], br[j], acc[i][j]);
        }
    }
    #pragma unroll
    for (int i = 0; i < 4; i++) {
        int m = bm + (ty << 2) + i;
        float* Cr = C + (size_t)m * N + bn;
        const float* Rr = resid ? resid + (size_t)m * N + bn : nullptr;
        #pragma unroll
        for (int j = 0; j < 4; j++) {
            int n = (tx << 2) + j;
            float v = acc[i][j];
            if (bias) v += bias[bn + n];
            if (Rr) v += Rr[n];
            if (RELU) v = fmaxf(v, 0.0f);
            Cr[n] = v;
        }
    }
}

// ---------------- attention scores: sc[b,h,q,k] = Q.K^T/8, masked ----------------
// grid: (SEQ/32, SEQ/32, NB*NH_). Q,K in (b*SEQ+s, h*64+d) layout.
__global__ __launch_bounds__(256)
void k_scores(const float* __restrict__ Q, const float* __restrict__ Kv,
              float* __restrict__ sc, const int* __restrict__ lengths, int causal)
{
    __shared__ float Qs[32][68];
    __shared__ float KsT[64][36];   // transposed: [d][k]
    int bh = blockIdx.z;
    int b = bh >> 3, hd = bh & 7;
    int q0 = blockIdx.y << 5, k0 = blockIdx.x << 5;
    int tid = threadIdx.x;
    for (int id = tid; id < 512; id += 256) {
        int r = id >> 4, c = (id & 15) << 2;
        float4 qv = *(const float4*)(Q  + (size_t)(b * SEQ + q0 + r) * HS_ + hd * 64 + c);
        float4 kv = *(const float4*)(Kv + (size_t)(b * SEQ + k0 + r) * HS_ + hd * 64 + c);
        *(float4*)&Qs[r][c] = qv;
        KsT[c + 0][r] = kv.x;
        KsT[c + 1][r] = kv.y;
        KsT[c + 2][r] = kv.z;
        KsT[c + 3][r] = kv.w;
    }
    __syncthreads();
    int tx = tid & 15, ty = tid >> 4;
    float acc[2][2] = {};
    #pragma unroll 4
    for (int d = 0; d < 64; d++) {
        float qa = Qs[ty * 2 + 0][d];
        float qb = Qs[ty * 2 + 1][d];
        float ka = KsT[d][tx * 2 + 0];
        float kb = KsT[d][tx * 2 + 1];
        acc[0][0] = fmaf(qa, ka, acc[0][0]);
        acc[0][1] = fmaf(qa, kb, acc[0][1]);
        acc[1][0] = fmaf(qb, ka, acc[1][0]);
        acc[1][1] = fmaf(qb, kb, acc[1][1]);
    }
    const float NEGINF = -__builtin_inff();
    int len = causal ? 0 : lengths[b];
    #pragma unroll
    for (int i = 0; i < 2; i++) {
        int q = q0 + ty * 2 + i;
        #pragma unroll
        for (int j = 0; j < 2; j++) {
            int k = k0 + tx * 2 + j;
            bool msk = causal ? (k > q) : (k >= len);
            sc[((size_t)bh * SEQ + q) * SEQ + k] = msk ? NEGINF : acc[i][j] * 0.125f;
        }
    }
}

// ---------------- row softmax over 512, one wave per row, in place ----------------
__global__ __launch_bounds__(64)
void k_softmax(float* __restrict__ sc)
{
    float* x = sc + (size_t)blockIdx.x * SEQ;
    int lane = threadIdx.x;
    float4 a = *(const float4*)(x + lane * 8);
    float4 b = *(const float4*)(x + lane * 8 + 4);
    float v[8] = {a.x, a.y, a.z, a.w, b.x, b.y, b.z, b.w};
    float mx = v[0];
    #pragma unroll
    for (int i = 1; i < 8; i++) mx = fmaxf(mx, v[i]);
    #pragma unroll
    for (int off = 32; off; off >>= 1) mx = fmaxf(mx, __shfl_xor(mx, off));
    float s = 0.f;
    #pragma unroll
    for (int i = 0; i < 8; i++) { v[i] = expf(v[i] - mx); s += v[i]; }
    #pragma unroll
    for (int off = 32; off; off >>= 1) s += __shfl_xor(s, off);
    float inv = 1.0f / s;
    #pragma unroll
    for (int i = 0; i < 8; i++) v[i] *= inv;
    *(float4*)(x + lane * 8)     = make_float4(v[0], v[1], v[2], v[3]);
    *(float4*)(x + lane * 8 + 4) = make_float4(v[4], v[5], v[6], v[7]);
}

// ---------------- ctx[b,q,h*64+d] = P[b,h,q,:] @ V[b,:,h*64+d] ----------------
// grid: (SEQ/64, NB*NH_). 64x64 output tile (d-dim = 64 full), BK=16.
__global__ __launch_bounds__(256)
void k_ctx(const float* __restrict__ P, const float* __restrict__ V,
           float* __restrict__ ctx)
{
    __shared__ float Ps[16][68];
    __shared__ float Vs[16][68];
    int bh = blockIdx.y;
    int b = bh >> 3, hd = bh & 7;
    int q0 = blockIdx.x << 6;
    int tid = threadIdx.x;
    int tx = tid & 15, ty = tid >> 4;
    int pm = tid >> 2, pk = (tid & 3) << 2;
    int vk = tid >> 4, vd = (tid & 15) << 2;
    const float* Pb = P + (size_t)bh * SEQ * SEQ;
    float acc[4][4] = {};
    for (int k0 = 0; k0 < SEQ; k0 += 16) {
        float4 pv = *(const float4*)(Pb + (size_t)(q0 + pm) * SEQ + k0 + pk);
        float4 vv = *(const float4*)(V + (size_t)(b * SEQ + k0 + vk) * HS_ + hd * 64 + vd);
        __syncthreads();
        Ps[pk + 0][pm] = pv.x;
        Ps[pk + 1][pm] = pv.y;
        Ps[pk + 2][pm] = pv.z;
        Ps[pk + 3][pm] = pv.w;
        *(float4*)&Vs[vk][vd] = vv;
        __syncthreads();
        #pragma unroll
        for (int k = 0; k < 16; k++) {
            float4 a4 = *(const float4*)&Ps[k][ty << 2];
            float4 b4 = *(const float4*)&Vs[k][tx << 2];
            float ar[4] = {a4.x, a4.y, a4.z, a4.w};
            float br[4] = {b4.x, b4.y, b4.z, b4.w};
            #pragma unroll
            for (int i = 0; i < 4; i++)
                #pragma unroll
                for (int j = 0; j < 4; j++)
                    acc[i][j] = fmaf(ar[i], br[j], acc[i][j]);
        }
    }
    #pragma unroll
    for (int i = 0; i < 4; i++) {
        int q = q0 + (ty << 2) + i;
        #pragma unroll
        for (int j = 0; j < 4; j++)
            ctx[(size_t)(b * SEQ + q) * HS_ + hd * 64 + (tx << 2) + j] = acc[i][j];
    }
}

// ---------------- log-softmax in place over rows of VOC_ ----------------
__global__ __launch_bounds__(256)
void k_logsoftmax(float* __restrict__ out)
{
    __shared__ float red[4];
    int row = blockIdx.x;
    float* x = out + (size_t)row * VOC_;
    int tid = threadIdx.x;

    float mx = -3.4e38f;
    for (int i = tid; i < VOC_ / 4; i += 256) {
        float4 v = ((const float4*)x)[i];
        mx = fmaxf(fmaxf(v.x, v.y), fmaxf(fmaxf(v.z, v.w), mx));
    }
    #pragma unroll
    for (int off = 32; off; off >>= 1) mx = fmaxf(mx, __shfl_xor(mx, off));
    if ((tid & 63) == 0) red[tid >> 6] = mx;
    __syncthreads();
    mx = fmaxf(fmaxf(red[0], red[1]), fmaxf(red[2], red[3]));
    __syncthreads();

    float s = 0.f;
    for (int i = tid; i < VOC_ / 4; i += 256) {
        float4 v = ((const float4*)x)[i];
        s += expf(v.x - mx) + expf(v.y - mx) + expf(v.z - mx) + expf(v.w - mx);
    }
    #pragma unroll
    for (int off = 32; off; off >>= 1) s += __shfl_xor(s, off);
    if ((tid & 63) == 0) red[tid >> 6] = s;
    __syncthreads();
    float lse = mx + logf(red[0] + red[1] + red[2] + red[3]);

    for (int i = tid; i < VOC_ / 4; i += 256) {
        float4 v = ((const float4*)x)[i];
        v.x -= lse; v.y -= lse; v.z -= lse; v.w -= lse;
        ((float4*)x)[i] = v;
    }
}

} // namespace

extern "C" void kernel_launch(void* const* d_in, const int* in_sizes, int n_in,
                              void* d_out, int out_size, void* d_ws, size_t ws_size,
                              hipStream_t stream)
{
    (void)in_sizes; (void)n_in; (void)out_size; (void)ws_size;
    const int*   x_tokens = (const int*)d_in[0];
    const int*   lengths  = (const int*)d_in[1];
    const int*   y_tokens = (const int*)d_in[2];
    const float* emb_enc  = (const float*)d_in[3];
    const float* emb_dec  = (const float*)d_in[4];
    const float* eWq  = (const float*)d_in[5];
    const float* eWk  = (const float*)d_in[6];
    const float* eWv  = (const float*)d_in[7];
    const float* eWo  = (const float*)d_in[8];
    const float* eln1g = (const float*)d_in[9];
    const float* eln1b = (const float*)d_in[10];
    const float* eln2g = (const float*)d_in[11];
    const float* eln2b = (const float*)d_in[12];
    const float* eW1  = (const float*)d_in[13];
    const float* eb1  = (const float*)d_in[14];
    const float* eW2  = (const float*)d_in[15];
    const float* eb2  = (const float*)d_in[16];
    const float* dsWq = (const float*)d_in[17];
    const float* dsWk = (const float*)d_in[18];
    const float* dsWv = (const float*)d_in[19];
    const float* dsWo = (const float*)d_in[20];
    const float* dcWq = (const float*)d_in[21];
    const float* dcWk = (const float*)d_in[22];
    const float* dcWv = (const float*)d_in[23];
    const float* dcWo = (const float*)d_in[24];
    const float* dln1g = (const float*)d_in[25];
    const float* dln1b = (const float*)d_in[26];
    const float* dln2g = (const float*)d_in[27];
    const float* dln2b = (const float*)d_in[28];
    const float* dln3g = (const float*)d_in[29];
    const float* dln3b = (const float*)d_in[30];
    const float* dW1  = (const float*)d_in[31];
    const float* db1  = (const float*)d_in[32];
    const float* dW2  = (const float*)d_in[33];
    const float* db2  = (const float*)d_in[34];
    const float* glng = (const float*)d_in[35];
    const float* glnb = (const float*)d_in[36];
    const float* gW   = (const float*)d_in[37];
    const float* gb   = (const float*)d_in[38];

    float* ws = (float*)d_ws;
    const size_t MH = (size_t)MT * HS_;       // 1M floats
    float* z    = ws;                         // encoder state
    float* h    = z + MH;                     // decoder state
    float* hn   = h + MH;                     // LN scratch
    float* kv   = hn + MH;                    // cross-attn kv (LN of z)
    float* Qb   = kv + MH;
    float* Kb   = Qb + MH;
    float* Vb   = Kb + MH;
    float* ctxb = Vb + MH;
    float* big  = ctxb + MH;                  // shared: scores (8M) / ffn (4M)
    float* sc   = big;
    float* ffn  = big;

    auto gemm = [&](const float* A, const float* W, const float* bias,
                    const float* resid, float* C, int M, int N, int K, bool relu) {
        dim3 g(N / 64, M / 64);
        if (relu) k_gemm<1><<<g, 256, 0, stream>>>(A, W, bias, resid, C, M, N, K);
        else      k_gemm<0><<<g, 256, 0, stream>>>(A, W, bias, resid, C, M, N, K);
    };
    auto ln = [&](const float* x, const float* g, const float* b, float* o) {
        k_ln<<<MT, 64, 0, stream>>>(x, g, b, o);
    };
    auto attn = [&](const float* qin, const float* kvin,
                    const float* Wq, const float* Wk, const float* Wv, const float* Wo,
                    float* io, int causal) {
        gemm(qin,  Wq, nullptr, nullptr, Qb, MT, HS_, HS_, false);
        gemm(kvin, Wk, nullptr, nullptr, Kb, MT, HS_, HS_, false);
        gemm(kvin, Wv, nullptr, nullptr, Vb, MT, HS_, HS_, false);
        k_scores<<<dim3(SEQ / 32, SEQ / 32, NB * NH_), 256, 0, stream>>>(Qb, Kb, sc, lengths, causal);
        k_softmax<<<NB * NH_ * SEQ, 64, 0, stream>>>(sc);
        k_ctx<<<dim3(SEQ / 64, NB * NH_), 256, 0, stream>>>(sc, Vb, ctxb);
        gemm(ctxb, Wo, nullptr, io, io, MT, HS_, HS_, false);
    };

    const size_t WHH = (size_t)HS_ * HS_;
    const size_t WHF = (size_t)HS_ * FF_;

    // ---------------- encoder ----------------
    k_embed<<<MT, 256, 0, stream>>>(x_tokens, emb_enc, z);
    for (int i = 0; i < NL_; i++) {
        ln(z, eln1g + i * HS_, eln1b + i * HS_, hn);
        attn(hn, hn, eWq + i * WHH, eWk + i * WHH, eWv + i * WHH, eWo + i * WHH, z, 0);
        ln(z, eln2g + i * HS_, eln2b + i * HS_, hn);
        gemm(hn, eW1 + i * WHF, eb1 + i * FF_, nullptr, ffn, MT, FF_, HS_, true);
        gemm(ffn, eW2 + i * WHF, eb2 + i * HS_, z, z, MT, HS_, FF_, false);
    }

    // ---------------- decoder ----------------
    k_embed<<<MT, 256, 0, stream>>>(y_tokens, emb_dec, h);
    for (int i = 0; i < NL_; i++) {
        ln(h, dln1g + i * HS_, dln1b + i * HS_, hn);
        attn(hn, hn, dsWq + i * WHH, dsWk + i * WHH, dsWv + i * WHH, dsWo + i * WHH, h, 1);
        ln(z, dln2g + i * HS_, dln2b + i * HS_, kv);
        ln(h, dln2g + i * HS_, dln2b + i * HS_, hn);
        attn(hn, kv, dcWq + i * WHH, dcWk + i * WHH, dcWv + i * WHH, dcWo + i * WHH, h, 0);
        ln(h, dln3g + i * HS_, dln3b + i * HS_, hn);
        gemm(hn, dW1 + i * WHF, db1 + i * FF_, nullptr, ffn, MT, FF_, HS_, true);
        gemm(ffn, dW2 + i * WHF, db2 + i * HS_, h, h, MT, HS_, FF_, false);
    }

    // ---------------- generator ----------------
    ln(h, glng, glnb, hn);
    gemm(hn, gW, gb, nullptr, (float*)d_out, MT, VOC_, HS_, false);
    k_logsoftmax<<<MT, 256, 0, stream>>>((float*)d_out);
}

// Round 2
// 4137.836 us; speedup vs baseline: 1.8048x; 1.8048x over previous
//
#include <hip/hip_runtime.h>
#include <math.h>

namespace {

constexpr int NB   = 4;
constexpr int SEQ  = 512;
constexpr int HS_  = 512;
constexpr int NH_  = 8;
constexpr int NL_  = 6;
constexpr int FF_  = 2048;
constexpr int VOC_ = 32000;
constexpr int MT   = NB * SEQ;   // 2048 token rows

typedef __attribute__((ext_vector_type(8))) short short8;   // 8 bf16 = 4 VGPRs
typedef __attribute__((ext_vector_type(4))) float f32x4;    // MFMA accumulator
typedef unsigned short u16;

__device__ inline float b2f(u16 u) {
    unsigned i = ((unsigned)u) << 16; float f; __builtin_memcpy(&f, &i, 4); return f;
}
__device__ inline u16 f2b(float f) {
    unsigned i; __builtin_memcpy(&i, &f, 4);
    i += 0x7fffu + ((i >> 16) & 1u);            // round-nearest-even
    return (u16)(i >> 16);
}

// ---------------- embedding + sinusoidal positional encoding ----------------
__global__ __launch_bounds__(256)
void k_embed(const int* __restrict__ tok, const float* __restrict__ emb,
             float* __restrict__ out)
{
    int row = blockIdx.x;            // b*SEQ + s
    int s = row & (SEQ - 1);
    int t = tok[row];
    const float* e = emb + (size_t)t * HS_;
    float* o = out + (size_t)row * HS_;
    for (int i = threadIdx.x; i < HS_; i += 256) {
        int half = i >> 1;
        float freq = powf(10000.0f, -(float)half / (float)HS_);
        float ang = (float)s * freq;
        float pe = (i & 1) ? cosf(ang) : sinf(ang);
        o[i] = e[i] + pe;
    }
}

// ---------------- layernorm: one wave per row of 512, bf16 output ----------------
__global__ __launch_bounds__(64)
void k_ln(const float* __restrict__ in, const float* __restrict__ g,
          const float* __restrict__ b, u16* __restrict__ out)
{
    int row = blockIdx.x;
    int lane = threadIdx.x;
    const float* x = in + (size_t)row * HS_ + lane * 8;
    float4 u0 = *(const float4*)x;
    float4 u1 = *(const float4*)(x + 4);
    float v[8] = {u0.x, u0.y, u0.z, u0.w, u1.x, u1.y, u1.z, u1.w};
    float s = 0.f, s2 = 0.f;
    #pragma unroll
    for (int i = 0; i < 8; i++) { s += v[i]; s2 += v[i] * v[i]; }
    #pragma unroll
    for (int off = 32; off; off >>= 1) { s += __shfl_xor(s, off); s2 += __shfl_xor(s2, off); }
    float mean = s * (1.0f / HS_);
    float var  = s2 * (1.0f / HS_) - mean * mean;
    float rstd = rsqrtf(var + 1e-5f);
    const float* gp = g + lane * 8;
    const float* bp = b + lane * 8;
    float4 g0 = *(const float4*)gp, g1 = *(const float4*)(gp + 4);
    float4 b0 = *(const float4*)bp, b1 = *(const float4*)(bp + 4);
    float gv[8] = {g0.x, g0.y, g0.z, g0.w, g1.x, g1.y, g1.z, g1.w};
    float bv[8] = {b0.x, b0.y, b0.z, b0.w, b1.x, b1.y, b1.z, b1.w};
    unsigned w[4];
    #pragma unroll
    for (int j = 0; j < 4; j++) {
        u16 lo = f2b((v[2*j]   - mean) * rstd * gv[2*j]   + bv[2*j]);
        u16 hi = f2b((v[2*j+1] - mean) * rstd * gv[2*j+1] + bv[2*j+1]);
        w[j] = (unsigned)lo | ((unsigned)hi << 16);
    }
    int4 o; o.x = w[0]; o.y = w[1]; o.z = w[2]; o.w = w[3];
    *(int4*)(out + (size_t)row * HS_ + lane * 8) = o;
}

// ---------------- weight transpose+convert: W[K][N] fp32 -> Wt[N][K] bf16 ----------------
// grid: (K/32, N/32, nmat). dst row offset = z*N.
__global__ __launch_bounds__(256)
void k_wt(const float* __restrict__ s0, const float* __restrict__ s1,
          const float* __restrict__ s2, u16* __restrict__ dst, int K, int N)
{
    __shared__ float L[32][33];
    int z = blockIdx.z;
    const float* src = (z == 0) ? s0 : (z == 1) ? s1 : s2;
    int k0 = blockIdx.x << 5, n0 = blockIdx.y << 5;
    int t = threadIdx.x;
    int r = t >> 3, c4 = (t & 7) << 2;
    float4 v = *(const float4*)(src + (size_t)(k0 + r) * N + n0 + c4);
    L[r][c4 + 0] = v.x; L[r][c4 + 1] = v.y; L[r][c4 + 2] = v.z; L[r][c4 + 3] = v.w;
    __syncthreads();
    int n = t >> 3, kq = (t & 7) << 2;
    ushort4 o;
    o.x = f2b(L[kq + 0][n]);
    o.y = f2b(L[kq + 1][n]);
    o.z = f2b(L[kq + 2][n]);
    o.w = f2b(L[kq + 3][n]);
    *(ushort4*)&dst[(size_t)(z * N + n0 + n) * K + k0 + kq] = o;
}

// ---------------- bf16 MFMA GEMM: C[M][N] = A[M][K] @ Wt[N][K]^T ----------------
// 128x128 tile, BK=32, 256 threads (4 waves, 2x2), 4x4 16x16 frags per wave.
// LDS rows padded to 40 shorts (80B) -> <=2-way bank aliasing on ds_read_b128.
template<int RELU, int OUTBF>
__global__ __launch_bounds__(256)
void k_mm(const u16* __restrict__ A, const u16* __restrict__ Wt,
          const float* __restrict__ bias, const float* resid,
          void* Cout, int M, int N, int K, int ldc)
{
    __shared__ __align__(16) short As[128 * 40];
    __shared__ __align__(16) short Bs[128 * 40];
    const int tid  = threadIdx.x;
    const int lane = tid & 63;
    const int w    = tid >> 6;
    const int bn = blockIdx.x << 7, bm = blockIdx.y << 7;
    const int wm = (w >> 1) << 6, wn = (w & 1) << 6;
    const int fr = lane & 15, fs = lane >> 4;

    // staging: thread owns chunks (srow, sslot) and (srow+64, sslot); chunk = 8 bf16 = 16B
    const int srow = tid >> 2, sslot = tid & 3;
    const u16* Ap0 = A  + (size_t)(bm + srow) * K + sslot * 8;
    const u16* Ap1 = Ap0 + (size_t)64 * K;
    const u16* Bp0 = Wt + (size_t)(bn + srow) * K + sslot * 8;
    const u16* Bp1 = Bp0 + (size_t)64 * K;
    const int ldsA0 = srow * 40 + sslot * 8;
    const int ldsA1 = (srow + 64) * 40 + sslot * 8;

    // fragment read offsets (in shorts)
    int aoff[4], boff[4];
    #pragma unroll
    for (int i = 0; i < 4; i++) {
        aoff[i] = (wm + i * 16 + fr) * 40 + fs * 8;
        boff[i] = (wn + i * 16 + fr) * 40 + fs * 8;
    }

    f32x4 acc[4][4];
    #pragma unroll
    for (int i = 0; i < 4; i++)
        #pragma unroll
        for (int j = 0; j < 4; j++)
            acc[i][j] = (f32x4){0.f, 0.f, 0.f, 0.f};

    for (int k0 = 0; k0 < K; k0 += 32) {
        int4 a0 = *(const int4*)(Ap0 + k0);
        int4 a1 = *(const int4*)(Ap1 + k0);
        int4 b0 = *(const int4*)(Bp0 + k0);
        int4 b1 = *(const int4*)(Bp1 + k0);
        __syncthreads();
        *(int4*)&As[ldsA0] = a0;
        *(int4*)&As[ldsA1] = a1;
        *(int4*)&Bs[ldsA0] = b0;
        *(int4*)&Bs[ldsA1] = b1;
        __syncthreads();
        short8 av[4], bv[4];
        #pragma unroll
        for (int i = 0; i < 4; i++) av[i] = *(const short8*)&As[aoff[i]];
        #pragma unroll
        for (int i = 0; i < 4; i++) bv[i] = *(const short8*)&Bs[boff[i]];
        #pragma unroll
        for (int mi = 0; mi < 4; mi++)
            #pragma unroll
            for (int ni = 0; ni < 4; ni++)
                acc[mi][ni] = __builtin_amdgcn_mfma_f32_16x16x32_bf16(
                    av[mi], bv[ni], acc[mi][ni], 0, 0, 0);
    }

    // epilogue: C row = bm+wm+mi*16+fs*4+i, col = bn+wn+ni*16+fr
    #pragma unroll
    for (int mi = 0; mi < 4; mi++) {
        #pragma unroll
        for (int i = 0; i < 4; i++) {
            int row = bm + wm + mi * 16 + fs * 4 + i;
            #pragma unroll
            for (int ni = 0; ni < 4; ni++) {
                int ncol = bn + wn + ni * 16 + fr;
                float v = acc[mi][ni][i];
                if (bias)  v += bias[ncol];
                if (resid) v += resid[(size_t)row * ldc + ncol];
                if (RELU)  v = fmaxf(v, 0.0f);
                if (OUTBF) ((u16*)Cout)[(size_t)row * ldc + ncol] = f2b(v);
                else       ((float*)Cout)[(size_t)row * ldc + ncol] = v;
            }
        }
    }
}

// ---------------- attention scores: sc[b,h,q,k] = Q.K^T/8, masked (bf16 in) ----------------
__global__ __launch_bounds__(256)
void k_scores(const u16* __restrict__ Q, const u16* __restrict__ Kp, int ld,
              float* __restrict__ sc, const int* __restrict__ lengths, int causal)
{
    __shared__ float Qs[32][68];
    __shared__ float KsT[64][36];
    int bh = blockIdx.z;
    int b = bh >> 3, hd = bh & 7;
    int q0 = blockIdx.y << 5, k0 = blockIdx.x << 5;
    int t = threadIdx.x;
    int r = t >> 3, c8 = (t & 7) << 3;
    {
        int4 qv = *(const int4*)(Q  + (size_t)(b * SEQ + q0 + r) * ld + hd * 64 + c8);
        int4 kv = *(const int4*)(Kp + (size_t)(b * SEQ + k0 + r) * ld + hd * 64 + c8);
        unsigned qa[4] = {(unsigned)qv.x, (unsigned)qv.y, (unsigned)qv.z, (unsigned)qv.w};
        unsigned ka[4] = {(unsigned)kv.x, (unsigned)kv.y, (unsigned)kv.z, (unsigned)kv.w};
        #pragma unroll
        for (int j = 0; j < 4; j++) {
            Qs[r][c8 + 2 * j]     = b2f((u16)(qa[j] & 0xffffu));
            Qs[r][c8 + 2 * j + 1] = b2f((u16)(qa[j] >> 16));
            KsT[c8 + 2 * j][r]     = b2f((u16)(ka[j] & 0xffffu));
            KsT[c8 + 2 * j + 1][r] = b2f((u16)(ka[j] >> 16));
        }
    }
    __syncthreads();
    int tx = t & 15, ty = t >> 4;
    float acc[2][2] = {};
    #pragma unroll 4
    for (int d = 0; d < 64; d++) {
        float qa = Qs[ty * 2 + 0][d];
        float qb = Qs[ty * 2 + 1][d];
        float ka = KsT[d][tx * 2 + 0];
        float kb = KsT[d][tx * 2 + 1];
        acc[0][0] = fmaf(qa, ka, acc[0][0]);
        acc[0][1] = fmaf(qa, kb, acc[0][1]);
        acc[1][0] = fmaf(qb, ka, acc[1][0]);
        acc[1][1] = fmaf(qb, kb, acc[1][1]);
    }
    const float NEGINF = -__builtin_inff();
    int len = causal ? 0 : lengths[b];
    #pragma unroll
    for (int i = 0; i < 2; i++) {
        int q = q0 + ty * 2 + i;
        #pragma unroll
        for (int j = 0; j < 2; j++) {
            int k = k0 + tx * 2 + j;
            bool msk = causal ? (k > q) : (k >= len);
            sc[((size_t)bh * SEQ + q) * SEQ + k] = msk ? NEGINF : acc[i][j] * 0.125f;
        }
    }
}

// ---------------- row softmax over 512, one wave per row, in place ----------------
__global__ __launch_bounds__(64)
void k_softmax(float* __restrict__ sc)
{
    float* x = sc + (size_t)blockIdx.x * SEQ;
    int lane = threadIdx.x;
    float4 a = *(const float4*)(x + lane * 8);
    float4 b = *(const float4*)(x + lane * 8 + 4);
    float v[8] = {a.x, a.y, a.z, a.w, b.x, b.y, b.z, b.w};
    float mx = v[0];
    #pragma unroll
    for (int i = 1; i < 8; i++) mx = fmaxf(mx, v[i]);
    #pragma unroll
    for (int off = 32; off; off >>= 1) mx = fmaxf(mx, __shfl_xor(mx, off));
    float s = 0.f;
    #pragma unroll
    for (int i = 0; i < 8; i++) { v[i] = expf(v[i] - mx); s += v[i]; }
    #pragma unroll
    for (int off = 32; off; off >>= 1) s += __shfl_xor(s, off);
    float inv = 1.0f / s;
    #pragma unroll
    for (int i = 0; i < 8; i++) v[i] *= inv;
    *(float4*)(x + lane * 8)     = make_float4(v[0], v[1], v[2], v[3]);
    *(float4*)(x + lane * 8 + 4) = make_float4(v[4], v[5], v[6], v[7]);
}

// ---------------- ctx = P @ V (V bf16, ctx bf16 out) ----------------
__global__ __launch_bounds__(256)
void k_ctx(const float* __restrict__ P, const u16* __restrict__ V, int ldv,
           u16* __restrict__ ctx)
{
    __shared__ float Ps[16][68];
    __shared__ float Vs[16][68];
    int bh = blockIdx.y;
    int b = bh >> 3, hd = bh & 7;
    int q0 = blockIdx.x << 6;
    int tid = threadIdx.x;
    int tx = tid & 15, ty = tid >> 4;
    int pm = tid >> 2, pk = (tid & 3) << 2;
    int vk = tid >> 4, vd = (tid & 15) << 2;
    const float* Pb = P + (size_t)bh * SEQ * SEQ;
    float acc[4][4] = {};
    for (int k0 = 0; k0 < SEQ; k0 += 16) {
        float4 pv = *(const float4*)(Pb + (size_t)(q0 + pm) * SEQ + k0 + pk);
        ushort4 vv = *(const ushort4*)(V + (size_t)(b * SEQ + k0 + vk) * ldv + hd * 64 + vd);
        __syncthreads();
        Ps[pk + 0][pm] = pv.x;
        Ps[pk + 1][pm] = pv.y;
        Ps[pk + 2][pm] = pv.z;
        Ps[pk + 3][pm] = pv.w;
        Vs[vk][vd + 0] = b2f(vv.x);
        Vs[vk][vd + 1] = b2f(vv.y);
        Vs[vk][vd + 2] = b2f(vv.z);
        Vs[vk][vd + 3] = b2f(vv.w);
        __syncthreads();
        #pragma unroll
        for (int k = 0; k < 16; k++) {
            float4 a4 = *(const float4*)&Ps[k][ty << 2];
            float4 b4 = *(const float4*)&Vs[k][tx << 2];
            float ar[4] = {a4.x, a4.y, a4.z, a4.w};
            float br[4] = {b4.x, b4.y, b4.z, b4.w};
            #pragma unroll
            for (int i = 0; i < 4; i++)
                #pragma unroll
                for (int j = 0; j < 4; j++)
                    acc[i][j] = fmaf(ar[i], br[j], acc[i][j]);
        }
    }
    #pragma unroll
    for (int i = 0; i < 4; i++) {
        int q = q0 + (ty << 2) + i;
        ushort4 o;
        o.x = f2b(acc[i][0]); o.y = f2b(acc[i][1]);
        o.z = f2b(acc[i][2]); o.w = f2b(acc[i][3]);
        *(ushort4*)&ctx[(size_t)(b * SEQ + q) * HS_ + hd * 64 + (tx << 2)] = o;
    }
}

// ---------------- log-softmax in place over rows of VOC_ ----------------
__global__ __launch_bounds__(256)
void k_logsoftmax(float* __restrict__ out)
{
    __shared__ float red[4];
    int row = blockIdx.x;
    float* x = out + (size_t)row * VOC_;
    int tid = threadIdx.x;

    float mx = -3.4e38f;
    for (int i = tid; i < VOC_ / 4; i += 256) {
        float4 v = ((const float4*)x)[i];
        mx = fmaxf(fmaxf(v.x, v.y), fmaxf(fmaxf(v.z, v.w), mx));
    }
    #pragma unroll
    for (int off = 32; off; off >>= 1) mx = fmaxf(mx, __shfl_xor(mx, off));
    if ((tid & 63) == 0) red[tid >> 6] = mx;
    __syncthreads();
    mx = fmaxf(fmaxf(red[0], red[1]), fmaxf(red[2], red[3]));
    __syncthreads();

    float s = 0.f;
    for (int i = tid; i < VOC_ / 4; i += 256) {
        float4 v = ((const float4*)x)[i];
        s += expf(v.x - mx) + expf(v.y - mx) + expf(v.z - mx) + expf(v.w - mx);
    }
    #pragma unroll
    for (int off = 32; off; off >>= 1) s += __shfl_xor(s, off);
    if ((tid & 63) == 0) red[tid >> 6] = s;
    __syncthreads();
    float lse = mx + logf(red[0] + red[1] + red[2] + red[3]);

    for (int i = tid; i < VOC_ / 4; i += 256) {
        float4 v = ((const float4*)x)[i];
        v.x -= lse; v.y -= lse; v.z -= lse; v.w -= lse;
        ((float4*)x)[i] = v;
    }
}

} // namespace

extern "C" void kernel_launch(void* const* d_in, const int* in_sizes, int n_in,
                              void* d_out, int out_size, void* d_ws, size_t ws_size,
                              hipStream_t stream)
{
    (void)in_sizes; (void)n_in; (void)out_size; (void)ws_size;
    const int*   x_tokens = (const int*)d_in[0];
    const int*   lengths  = (const int*)d_in[1];
    const int*   y_tokens = (const int*)d_in[2];
    const float* emb_enc  = (const float*)d_in[3];
    const float* emb_dec  = (const float*)d_in[4];
    const float* eWq  = (const float*)d_in[5];
    const float* eWk  = (const float*)d_in[6];
    const float* eWv  = (const float*)d_in[7];
    const float* eWo  = (const float*)d_in[8];
    const float* eln1g = (const float*)d_in[9];
    const float* eln1b = (const float*)d_in[10];
    const float* eln2g = (const float*)d_in[11];
    const float* eln2b = (const float*)d_in[12];
    const float* eW1  = (const float*)d_in[13];
    const float* eb1  = (const float*)d_in[14];
    const float* eW2  = (const float*)d_in[15];
    const float* eb2  = (const float*)d_in[16];
    const float* dsWq = (const float*)d_in[17];
    const float* dsWk = (const float*)d_in[18];
    const float* dsWv = (const float*)d_in[19];
    const float* dsWo = (const float*)d_in[20];
    const float* dcWq = (const float*)d_in[21];
    const float* dcWk = (const float*)d_in[22];
    const float* dcWv = (const float*)d_in[23];
    const float* dcWo = (const float*)d_in[24];
    const float* dln1g = (const float*)d_in[25];
    const float* dln1b = (const float*)d_in[26];
    const float* dln2g = (const float*)d_in[27];
    const float* dln2b = (const float*)d_in[28];
    const float* dln3g = (const float*)d_in[29];
    const float* dln3b = (const float*)d_in[30];
    const float* dW1  = (const float*)d_in[31];
    const float* db1  = (const float*)d_in[32];
    const float* dW2  = (const float*)d_in[33];
    const float* db2  = (const float*)d_in[34];
    const float* glng = (const float*)d_in[35];
    const float* glnb = (const float*)d_in[36];
    const float* gW   = (const float*)d_in[37];
    const float* gb   = (const float*)d_in[38];

    const size_t MH = (size_t)MT * HS_;           // 1,048,576
    const size_t SCF = (size_t)NB * NH_ * SEQ * SEQ; // 8,388,608 floats

    float* z  = (float*)d_ws;
    float* h  = z + MH;
    float* sc = h + MH;                            // 33.5 MB fp32
    u16* ffnb = (u16*)sc;                          // overlay (disjoint in time)
    u16* vwt  = (u16*)sc;                          // overlay: vocab W^T (31.25 MB)
    u16* qkvb = (u16*)(sc + SCF);                  // [2048][1536]
    u16* hnb  = qkvb + (size_t)MT * 1536;
    u16* kvb  = hnb + MH;
    u16* ctxb = kvb + MH;
    u16* wtb  = ctxb + MH;                         // 4M bf16 = 8 MB per-layer weights

    // per-layer W^T offsets (bf16 elems) within wtb
    const size_t OF_QKV = 0;
    const size_t OF_WO  = 786432;
    const size_t OF_CQ  = 1048576;
    const size_t OF_CKV = 1310720;
    const size_t OF_CWO = 1835008;
    const size_t OF_W1  = 2097152;   // enc W1 uses this too
    const size_t OF_W2  = 3145728;   // enc uses OF_W1/OF_W2 slots below

    auto wconv = [&](const float* s0, const float* s1, const float* s2,
                     u16* dst, int K, int N, int nm) {
        k_wt<<<dim3(K / 32, N / 32, nm), 256, 0, stream>>>(
            s0, s1 ? s1 : s0, s2 ? s2 : s0, dst, K, N);
    };
    auto mm = [&](const u16* A, const u16* Wt, const float* bias, const float* resid,
                  void* C, int M, int N, int K, int ldc, int relu, int outbf) {
        dim3 g(N / 128, M / 128);
        if (relu)       k_mm<1, 1><<<g, 256, 0, stream>>>(A, Wt, bias, resid, C, M, N, K, ldc);
        else if (outbf) k_mm<0, 1><<<g, 256, 0, stream>>>(A, Wt, bias, resid, C, M, N, K, ldc);
        else            k_mm<0, 0><<<g, 256, 0, stream>>>(A, Wt, bias, resid, C, M, N, K, ldc);
    };
    auto ln = [&](const float* x, const float* g, const float* b, u16* o) {
        k_ln<<<MT, 64, 0, stream>>>(x, g, b, o);
    };
    auto attncore = [&](const u16* qkv, u16* ctxo, int causal) {
        k_scores<<<dim3(SEQ / 32, SEQ / 32, NB * NH_), 256, 0, stream>>>(
            qkv, qkv + 512, 1536, sc, lengths, causal);
        k_softmax<<<NB * NH_ * SEQ, 64, 0, stream>>>(sc);
        k_ctx<<<dim3(SEQ / 64, NB * NH_), 256, 0, stream>>>(sc, qkv + 1024, 1536, ctxo);
    };

    const size_t WHH = (size_t)HS_ * HS_;
    const size_t WHF = (size_t)HS_ * FF_;

    // ---------------- encoder ----------------
    k_embed<<<MT, 256, 0, stream>>>(x_tokens, emb_enc, z);
    for (int i = 0; i < NL_; i++) {
        wconv(eWq + i * WHH, eWk + i * WHH, eWv + i * WHH, wtb + OF_QKV, HS_, HS_, 3);
        wconv(eWo + i * WHH, nullptr, nullptr, wtb + OF_WO, HS_, HS_, 1);
        wconv(eW1 + i * WHF, nullptr, nullptr, wtb + OF_W1, HS_, FF_, 1);
        wconv(eW2 + i * WHF, nullptr, nullptr, wtb + OF_W2, FF_, HS_, 1);

        ln(z, eln1g + i * HS_, eln1b + i * HS_, hnb);
        mm(hnb, wtb + OF_QKV, nullptr, nullptr, qkvb, MT, 1536, HS_, 1536, 0, 1);
        attncore(qkvb, ctxb, 0);
        mm(ctxb, wtb + OF_WO, nullptr, z, z, MT, HS_, HS_, HS_, 0, 0);

        ln(z, eln2g + i * HS_, eln2b + i * HS_, hnb);
        mm(hnb, wtb + OF_W1, eb1 + i * FF_, nullptr, ffnb, MT, FF_, HS_, FF_, 1, 1);
        mm(ffnb, wtb + OF_W2, eb2 + i * HS_, z, z, MT, HS_, FF_, HS_, 0, 0);
    }

    // ---------------- decoder ----------------
    k_embed<<<MT, 256, 0, stream>>>(y_tokens, emb_dec, h);
    for (int i = 0; i < NL_; i++) {
        wconv(dsWq + i * WHH, dsWk + i * WHH, dsWv + i * WHH, wtb + OF_QKV, HS_, HS_, 3);
        wconv(dsWo + i * WHH, nullptr, nullptr, wtb + OF_WO, HS_, HS_, 1);
        wconv(dcWq + i * WHH, nullptr, nullptr, wtb + OF_CQ, HS_, HS_, 1);
        wconv(dcWk + i * WHH, dcWv + i * WHH, nullptr, wtb + OF_CKV, HS_, HS_, 2);
        wconv(dcWo + i * WHH, nullptr, nullptr, wtb + OF_CWO, HS_, HS_, 1);
        wconv(dW1 + i * WHF, nullptr, nullptr, wtb + OF_W1, HS_, FF_, 1);
        wconv(dW2 + i * WHF, nullptr, nullptr, wtb + OF_W2, FF_, HS_, 1);

        // self-attn (causal)
        ln(h, dln1g + i * HS_, dln1b + i * HS_, hnb);
        mm(hnb, wtb + OF_QKV, nullptr, nullptr, qkvb, MT, 1536, HS_, 1536, 0, 1);
        attncore(qkvb, ctxb, 1);
        mm(ctxb, wtb + OF_WO, nullptr, h, h, MT, HS_, HS_, HS_, 0, 0);

        // cross-attn
        ln(z, dln2g + i * HS_, dln2b + i * HS_, kvb);
        ln(h, dln2g + i * HS_, dln2b + i * HS_, hnb);
        mm(hnb, wtb + OF_CQ, nullptr, nullptr, qkvb, MT, HS_, HS_, 1536, 0, 1);
        mm(kvb, wtb + OF_CKV, nullptr, nullptr, qkvb + 512, MT, 1024, HS_, 1536, 0, 1);
        attncore(qkvb, ctxb, 0);
        mm(ctxb, wtb + OF_CWO, nullptr, h, h, MT, HS_, HS_, HS_, 0, 0);

        // FFN
        ln(h, dln3g + i * HS_, dln3b + i * HS_, hnb);
        mm(hnb, wtb + OF_W1, db1 + i * FF_, nullptr, ffnb, MT, FF_, HS_, FF_, 1, 1);
        mm(ffnb, wtb + OF_W2, db2 + i * HS_, h, h, MT, HS_, FF_, HS_, 0, 0);
    }

    // ---------------- generator ----------------
    k_wt<<<dim3(HS_ / 32, VOC_ / 32, 1), 256, 0, stream>>>(gW, gW, gW, vwt, HS_, VOC_);
    ln(h, glng, glnb, hnb);
    mm(hnb, vwt, gb, nullptr, (float*)d_out, MT, VOC_, HS_, VOC_, 0, 0);
    k_logsoftmax<<<MT, 256, 0, stream>>>((float*)d_out);
}